// Round 1
// baseline (3029.875 us; speedup 1.0000x reference)
//
#include <hip/hip_runtime.h>
#include <cstdint>
#include <cstddef>

typedef unsigned short u16;
typedef float f32x4 __attribute__((ext_vector_type(4)));
typedef __bf16 bf16x8 __attribute__((ext_vector_type(8)));

#define B_DIM   8192
#define IN_DIM  1024
#define HID_DIM 4096
#define OUT_DIM 1024
#define NEXP    8

// ---------- helpers ----------
__device__ __forceinline__ u16 f2b(float f) {
    uint32_t u = __builtin_bit_cast(uint32_t, f);
    u += 0x7fffu + ((u >> 16) & 1u);      // RNE
    return (u16)(u >> 16);
}
__device__ __forceinline__ float b2f(u16 b) {
    uint32_t u = ((uint32_t)b) << 16;
    return __builtin_bit_cast(float, u);
}
__device__ __forceinline__ float gelu_exact(float v) {
    return 0.5f * v * (1.0f + erff(v * 0.7071067811865475f));
}
__device__ __forceinline__ void async_cp16(const void* g, void* l) {
    __builtin_amdgcn_global_load_lds(
        (const __attribute__((address_space(1))) void*)g,
        (__attribute__((address_space(3))) void*)l,
        16, 0, 0);
}

// ---------- fp32 -> bf16 convert ----------
__global__ __launch_bounds__(256)
void cvt_bf16(const float* __restrict__ in, u16* __restrict__ out, int n4) {
    int i = blockIdx.x * 256 + threadIdx.x;
    if (i >= n4) return;
    float4 v = *(const float4*)&in[(size_t)i * 4];
    uint2 o;
    o.x = (uint32_t)f2b(v.x) | ((uint32_t)f2b(v.y) << 16);
    o.y = (uint32_t)f2b(v.z) | ((uint32_t)f2b(v.w) << 16);
    *(uint2*)&out[(size_t)i * 4] = o;
}

// ---------- transpose [K,N] fp32 -> [N,K] bf16 ----------
__global__ __launch_bounds__(256)
void transpose_cvt(const float* __restrict__ W, u16* __restrict__ Wt, int K, int N) {
    __shared__ float tile[32][33];
    const int n0 = blockIdx.x * 32, k0 = blockIdx.y * 32;
    const int tx = threadIdx.x & 31, ty = threadIdx.x >> 5;   // ty 0..7
#pragma unroll
    for (int i = 0; i < 4; ++i) {
        int k = k0 + ty + i * 8;
        tile[ty + i * 8][tx] = W[(size_t)k * N + n0 + tx];
    }
    __syncthreads();
#pragma unroll
    for (int i = 0; i < 4; ++i) {
        int n = n0 + ty + i * 8;
        Wt[(size_t)n * K + k0 + tx] = f2b(tile[tx][ty + i * 8]);
    }
}

// ---------- bf16 GEMM: C[M,N] = A[M,K] * Bt[N,K]^T + bias, out bf16 ----------
// m97 structure: 128x128 tile, BK=32, global_load_lds width-16 staging,
// 16x16x32 bf16 MFMA, 4 waves in 2x2, each wave 64x64 (4x4 MFMA tiles).
__global__ __launch_bounds__(256)
void gemm_bt_bias(const u16* __restrict__ A, const u16* __restrict__ Bt,
                  const float* __restrict__ bias, u16* __restrict__ C,
                  int M, int N, int K) {
    __shared__ __attribute__((aligned(16))) u16 sA[128 * 32];
    __shared__ __attribute__((aligned(16))) u16 sB[128 * 32];

    const int tid  = threadIdx.x;
    const int wid  = tid >> 6;
    const int lane = tid & 63;
    const int quad = lane >> 4;
    const int lr   = lane & 15;
    const int wm   = wid & 1;
    const int wn   = wid >> 1;

    const int m0 = blockIdx.y * 128;
    const int n0 = blockIdx.x * 128;

    const int sr = lane >> 2;          // 0..15 row within 16-row group
    const int sc = (lane & 3) * 8;     // element col (16B chunks)

    const u16* Ag = A + (size_t)m0 * K;
    const u16* Bg = Bt + (size_t)n0 * K;

    f32x4 acc[4][4] = {};

    for (int k0 = 0; k0 < K; k0 += 32) {
#pragma unroll
        for (int i = 0; i < 2; ++i) {
            const int rb = wid * 32 + i * 16;
            async_cp16(Ag + (size_t)(rb + sr) * K + k0 + sc, &sA[rb * 32]);
        }
#pragma unroll
        for (int i = 0; i < 2; ++i) {
            const int rb = wid * 32 + i * 16;
            async_cp16(Bg + (size_t)(rb + sr) * K + k0 + sc, &sB[rb * 32]);
        }
        __syncthreads();

        bf16x8 af[4], bfr[4];
#pragma unroll
        for (int mi = 0; mi < 4; ++mi)
            af[mi] = *(const bf16x8*)&sA[(wm * 64 + mi * 16 + lr) * 32 + quad * 8];
#pragma unroll
        for (int ni = 0; ni < 4; ++ni)
            bfr[ni] = *(const bf16x8*)&sB[(wn * 64 + ni * 16 + lr) * 32 + quad * 8];

#pragma unroll
        for (int mi = 0; mi < 4; ++mi)
#pragma unroll
            for (int ni = 0; ni < 4; ++ni)
                acc[mi][ni] = __builtin_amdgcn_mfma_f32_16x16x32_bf16(
                    af[mi], bfr[ni], acc[mi][ni], 0, 0, 0);

        __syncthreads();
    }

    // epilogue: D col = lane&15, row = quad*4 + reg
#pragma unroll
    for (int ni = 0; ni < 4; ++ni) {
        const int n = n0 + wn * 64 + ni * 16 + lr;
        const float bv = bias[n];
#pragma unroll
        for (int mi = 0; mi < 4; ++mi) {
            const int mr = m0 + wm * 64 + mi * 16 + quad * 4;
#pragma unroll
            for (int r = 0; r < 4; ++r) {
                C[(size_t)(mr + r) * N + n] = f2b(acc[mi][ni][r] + bv);
            }
        }
    }
}

// ---------- fused LN(4096) + GELU, in-place on bf16 h ----------
__global__ __launch_bounds__(256)
void ln_gelu_hid(u16* __restrict__ h, const float* __restrict__ g,
                 const float* __restrict__ be) {
    __shared__ float red[8];
    const int row = blockIdx.x;
    u16* hp = h + (size_t)row * HID_DIM;
    const int t = threadIdx.x;

    float vals[16];
    float s = 0.f, ss = 0.f;
#pragma unroll
    for (int j = 0; j < 2; ++j) {
        const int base = (t + j * 256) * 8;
        uint4 v = *(const uint4*)&hp[base];
        const uint32_t w[4] = {v.x, v.y, v.z, v.w};
#pragma unroll
        for (int q = 0; q < 4; ++q) {
            float f0 = b2f((u16)(w[q] & 0xffffu));
            float f1 = b2f((u16)(w[q] >> 16));
            vals[j * 8 + q * 2] = f0;
            vals[j * 8 + q * 2 + 1] = f1;
            s += f0 + f1;
            ss += f0 * f0 + f1 * f1;
        }
    }
#pragma unroll
    for (int off = 32; off > 0; off >>= 1) {
        s += __shfl_down(s, off, 64);
        ss += __shfl_down(ss, off, 64);
    }
    if ((t & 63) == 0) { red[(t >> 6) * 2] = s; red[(t >> 6) * 2 + 1] = ss; }
    __syncthreads();
    s  = red[0] + red[2] + red[4] + red[6];
    ss = red[1] + red[3] + red[5] + red[7];
    const float mean = s * (1.f / HID_DIM);
    const float rstd = rsqrtf(ss * (1.f / HID_DIM) - mean * mean + 1e-5f);

#pragma unroll
    for (int j = 0; j < 2; ++j) {
        const int base = (t + j * 256) * 8;
        uint4 o;
        uint32_t* ow = (uint32_t*)&o;
#pragma unroll
        for (int q = 0; q < 4; ++q) {
            const int i0 = base + q * 2;
            float v0 = gelu_exact((vals[j * 8 + q * 2]     - mean) * rstd * g[i0]     + be[i0]);
            float v1 = gelu_exact((vals[j * 8 + q * 2 + 1] - mean) * rstd * g[i0 + 1] + be[i0 + 1]);
            ow[q] = (uint32_t)f2b(v0) | ((uint32_t)f2b(v1) << 16);
        }
        *(uint4*)&hp[base] = o;
    }
}

// ---------- fused LN(1024) + GELU + weighted accumulate into out ----------
__global__ __launch_bounds__(256)
void ln_gelu_combine(const u16* __restrict__ y, const float* __restrict__ g,
                     const float* __restrict__ be, const float* __restrict__ wts,
                     float* __restrict__ out, int e) {
    __shared__ float red[8];
    const int row = blockIdx.x;
    const u16* yp = y + (size_t)row * OUT_DIM;
    const int t = threadIdx.x;

    uint2 v = *(const uint2*)&yp[t * 4];
    float f0 = b2f((u16)(v.x & 0xffffu)), f1 = b2f((u16)(v.x >> 16));
    float f2 = b2f((u16)(v.y & 0xffffu)), f3 = b2f((u16)(v.y >> 16));
    float s = f0 + f1 + f2 + f3;
    float ss = f0 * f0 + f1 * f1 + f2 * f2 + f3 * f3;
#pragma unroll
    for (int off = 32; off > 0; off >>= 1) {
        s += __shfl_down(s, off, 64);
        ss += __shfl_down(ss, off, 64);
    }
    if ((t & 63) == 0) { red[(t >> 6) * 2] = s; red[(t >> 6) * 2 + 1] = ss; }
    __syncthreads();
    s  = red[0] + red[2] + red[4] + red[6];
    ss = red[1] + red[3] + red[5] + red[7];
    const float mean = s * (1.f / OUT_DIM);
    const float rstd = rsqrtf(ss * (1.f / OUT_DIM) - mean * mean + 1e-5f);

    const float w = wts[(size_t)row * NEXP + e];
    const int n = t * 4;
    float4 gv = *(const float4*)&g[n];
    float4 bv = *(const float4*)&be[n];
    float4 o  = *(float4*)&out[(size_t)row * OUT_DIM + n];
    o.x += w * gelu_exact((f0 - mean) * rstd * gv.x + bv.x);
    o.y += w * gelu_exact((f1 - mean) * rstd * gv.y + bv.y);
    o.z += w * gelu_exact((f2 - mean) * rstd * gv.z + bv.z);
    o.w += w * gelu_exact((f3 - mean) * rstd * gv.w + bv.w);
    *(float4*)&out[(size_t)row * OUT_DIM + n] = o;
}

// ---------- launch ----------
extern "C" void kernel_launch(void* const* d_in, const int* in_sizes, int n_in,
                              void* d_out, int out_size, void* d_ws, size_t ws_size,
                              hipStream_t stream) {
    (void)in_sizes; (void)n_in; (void)out_size; (void)ws_size;
    const float* x   = (const float*)d_in[0];  // [8192,1024]
    const float* wts = (const float*)d_in[1];  // [8192,8]
    const float* W1  = (const float*)d_in[2];  // [8,1024,4096]
    const float* b1  = (const float*)d_in[3];  // [8,4096]
    const float* g1  = (const float*)d_in[4];  // [8,4096]
    const float* be1 = (const float*)d_in[5];  // [8,4096]
    const float* W2  = (const float*)d_in[6];  // [8,4096,1024]
    const float* b2  = (const float*)d_in[7];  // [8,1024]
    const float* g2  = (const float*)d_in[8];  // [8,1024]
    const float* be2 = (const float*)d_in[9];  // [8,1024]
    float* out = (float*)d_out;                // [8192,1024]

    // workspace carve (112 MB total)
    char* p = (char*)d_ws;
    u16* xb  = (u16*)p; p += (size_t)B_DIM * IN_DIM * 2;      // 16 MB
    u16* w1t = (u16*)p; p += (size_t)HID_DIM * IN_DIM * 2;    //  8 MB (per-expert slot)
    u16* w2t = (u16*)p; p += (size_t)OUT_DIM * HID_DIM * 2;   //  8 MB (per-expert slot)
    u16* h   = (u16*)p; p += (size_t)B_DIM * HID_DIM * 2;     // 64 MB
    u16* y   = (u16*)p; p += (size_t)B_DIM * OUT_DIM * 2;     // 16 MB

    hipMemsetAsync(d_out, 0, (size_t)B_DIM * OUT_DIM * sizeof(float), stream);

    cvt_bf16<<<(B_DIM * IN_DIM / 4 + 255) / 256, 256, 0, stream>>>(x, xb, B_DIM * IN_DIM / 4);

    for (int e = 0; e < NEXP; ++e) {
        // W1[e]: [IN,HID] -> w1t [HID,IN]
        transpose_cvt<<<dim3(HID_DIM / 32, IN_DIM / 32), 256, 0, stream>>>(
            W1 + (size_t)e * IN_DIM * HID_DIM, w1t, IN_DIM, HID_DIM);
        // h = xb @ W1[e] + b1[e]   (M=8192, N=4096, K=1024)
        gemm_bt_bias<<<dim3(HID_DIM / 128, B_DIM / 128), 256, 0, stream>>>(
            xb, w1t, b1 + (size_t)e * HID_DIM, h, B_DIM, HID_DIM, IN_DIM);
        // h = gelu(ln(h))
        ln_gelu_hid<<<B_DIM, 256, 0, stream>>>(h, g1 + (size_t)e * HID_DIM,
                                               be1 + (size_t)e * HID_DIM);
        // W2[e]: [HID,OUT] -> w2t [OUT,HID]
        transpose_cvt<<<dim3(OUT_DIM / 32, HID_DIM / 32), 256, 0, stream>>>(
            W2 + (size_t)e * HID_DIM * OUT_DIM, w2t, HID_DIM, OUT_DIM);
        // y = h @ W2[e] + b2[e]   (M=8192, N=1024, K=4096)
        gemm_bt_bias<<<dim3(OUT_DIM / 128, B_DIM / 128), 256, 0, stream>>>(
            h, w2t, b2 + (size_t)e * OUT_DIM, y, B_DIM, OUT_DIM, HID_DIM);
        // out += wts[:,e] * gelu(ln(y))
        ln_gelu_combine<<<B_DIM, 256, 0, stream>>>(y, g2 + (size_t)e * OUT_DIM,
                                                   be2 + (size_t)e * OUT_DIM, wts, out, e);
    }
}

// Round 2
// 2282.458 us; speedup vs baseline: 1.3275x; 1.3275x over previous
//
#include <hip/hip_runtime.h>
#include <cstdint>
#include <cstddef>

typedef unsigned short u16;
typedef float f32x4 __attribute__((ext_vector_type(4)));
typedef __bf16 bf16x8 __attribute__((ext_vector_type(8)));

#define B_DIM   8192
#define IN_DIM  1024
#define HID_DIM 4096
#define OUT_DIM 1024
#define NEXP    8

// ---------- helpers ----------
__device__ __forceinline__ u16 f2b(float f) {
    uint32_t u = __builtin_bit_cast(uint32_t, f);
    u += 0x7fffu + ((u >> 16) & 1u);      // RNE
    return (u16)(u >> 16);
}
__device__ __forceinline__ float b2f(u16 b) {
    uint32_t u = ((uint32_t)b) << 16;
    return __builtin_bit_cast(float, u);
}
// tanh-form GELU via one v_exp_f32: gelu(x) = x * e/(e+1), e = exp(2*y),
// y = c0*x + c0*c1*x^3. Exponent clamped so e=inf never produces NaN.
__device__ __forceinline__ float gelu_fast(float x) {
    float y = x * (0.7978845608f + 0.03567740814f * x * x);
    float a = fminf(y * 2.8853900818f, 80.0f);     // 2*log2(e)*y, clamp overflow
    float e = __builtin_amdgcn_exp2f(a);
    return x * e * __builtin_amdgcn_rcpf(e + 1.0f);
}
__device__ __forceinline__ void async_cp16(const void* g, void* l) {
    __builtin_amdgcn_global_load_lds(
        (const __attribute__((address_space(1))) void*)g,
        (__attribute__((address_space(3))) void*)l,
        16, 0, 0);
}

// ---------- fp32 -> bf16 convert ----------
__global__ __launch_bounds__(256)
void cvt_bf16(const float* __restrict__ in, u16* __restrict__ out, int n4) {
    int i = blockIdx.x * 256 + threadIdx.x;
    if (i >= n4) return;
    float4 v = *(const float4*)&in[(size_t)i * 4];
    uint2 o;
    o.x = (uint32_t)f2b(v.x) | ((uint32_t)f2b(v.y) << 16);
    o.y = (uint32_t)f2b(v.z) | ((uint32_t)f2b(v.w) << 16);
    *(uint2*)&out[(size_t)i * 4] = o;
}

// ---------- transpose [K,N] fp32 -> [N,K] bf16 ----------
__global__ __launch_bounds__(256)
void transpose_cvt(const float* __restrict__ W, u16* __restrict__ Wt, int K, int N) {
    __shared__ float tile[32][33];
    const int n0 = blockIdx.x * 32, k0 = blockIdx.y * 32;
    const int tx = threadIdx.x & 31, ty = threadIdx.x >> 5;   // ty 0..7
#pragma unroll
    for (int i = 0; i < 4; ++i) {
        int k = k0 + ty + i * 8;
        tile[ty + i * 8][tx] = W[(size_t)k * N + n0 + tx];
    }
    __syncthreads();
#pragma unroll
    for (int i = 0; i < 4; ++i) {
        int n = n0 + ty + i * 8;
        Wt[(size_t)n * K + k0 + tx] = f2b(tile[tx][ty + i * 8]);
    }
}

// ---------- bf16 GEMM: C[M,N] = A[M,K] * Bt[N,K]^T + bias, out bf16 ----------
// m97 structure: 128x128 tile, BK=32, global_load_lds width-16 staging,
// 16x16x32 bf16 MFMA, 4 waves in 2x2, each wave 64x64 (4x4 MFMA tiles).
__global__ __launch_bounds__(256)
void gemm_bt_bias(const u16* __restrict__ A, const u16* __restrict__ Bt,
                  const float* __restrict__ bias, u16* __restrict__ C,
                  int M, int N, int K) {
    __shared__ __attribute__((aligned(16))) u16 sA[128 * 32];
    __shared__ __attribute__((aligned(16))) u16 sB[128 * 32];

    const int tid  = threadIdx.x;
    const int wid  = tid >> 6;
    const int lane = tid & 63;
    const int quad = lane >> 4;
    const int lr   = lane & 15;
    const int wm   = wid & 1;
    const int wn   = wid >> 1;

    const int m0 = blockIdx.y * 128;
    const int n0 = blockIdx.x * 128;

    const int sr = lane >> 2;          // 0..15 row within 16-row group
    const int sc = (lane & 3) * 8;     // element col (16B chunks)

    const u16* Ag = A + (size_t)m0 * K;
    const u16* Bg = Bt + (size_t)n0 * K;

    f32x4 acc[4][4] = {};

    for (int k0 = 0; k0 < K; k0 += 32) {
#pragma unroll
        for (int i = 0; i < 2; ++i) {
            const int rb = wid * 32 + i * 16;
            async_cp16(Ag + (size_t)(rb + sr) * K + k0 + sc, &sA[rb * 32]);
        }
#pragma unroll
        for (int i = 0; i < 2; ++i) {
            const int rb = wid * 32 + i * 16;
            async_cp16(Bg + (size_t)(rb + sr) * K + k0 + sc, &sB[rb * 32]);
        }
        __syncthreads();

        bf16x8 af[4], bfr[4];
#pragma unroll
        for (int mi = 0; mi < 4; ++mi)
            af[mi] = *(const bf16x8*)&sA[(wm * 64 + mi * 16 + lr) * 32 + quad * 8];
#pragma unroll
        for (int ni = 0; ni < 4; ++ni)
            bfr[ni] = *(const bf16x8*)&sB[(wn * 64 + ni * 16 + lr) * 32 + quad * 8];

#pragma unroll
        for (int mi = 0; mi < 4; ++mi)
#pragma unroll
            for (int ni = 0; ni < 4; ++ni)
                acc[mi][ni] = __builtin_amdgcn_mfma_f32_16x16x32_bf16(
                    af[mi], bfr[ni], acc[mi][ni], 0, 0, 0);

        __syncthreads();
    }

    // epilogue: D col = lane&15, row = quad*4 + reg
#pragma unroll
    for (int ni = 0; ni < 4; ++ni) {
        const int n = n0 + wn * 64 + ni * 16 + lr;
        const float bv = bias[n];
#pragma unroll
        for (int mi = 0; mi < 4; ++mi) {
            const int mr = m0 + wm * 64 + mi * 16 + quad * 4;
#pragma unroll
            for (int r = 0; r < 4; ++r) {
                C[(size_t)(mr + r) * N + n] = f2b(acc[mi][ni][r] + bv);
            }
        }
    }
}

// ---------- fused LN(4096) + GELU, in-place on bf16 h ----------
__global__ __launch_bounds__(256)
void ln_gelu_hid(u16* __restrict__ h, const float* __restrict__ g,
                 const float* __restrict__ be) {
    __shared__ float red[8];
    const int row = blockIdx.x;
    u16* hp = h + (size_t)row * HID_DIM;
    const int t = threadIdx.x;

    // load 16 bf16 elements (2x uint4)
    uint4 v0 = *(const uint4*)&hp[t * 8];
    uint4 v1 = *(const uint4*)&hp[(t + 256) * 8];

    float vals[16];
    {
        const uint32_t w0[4] = {v0.x, v0.y, v0.z, v0.w};
        const uint32_t w1[4] = {v1.x, v1.y, v1.z, v1.w};
#pragma unroll
        for (int q = 0; q < 4; ++q) {
            vals[q * 2]     = b2f((u16)(w0[q] & 0xffffu));
            vals[q * 2 + 1] = b2f((u16)(w0[q] >> 16));
            vals[8 + q * 2]     = b2f((u16)(w1[q] & 0xffffu));
            vals[8 + q * 2 + 1] = b2f((u16)(w1[q] >> 16));
        }
    }
    float s = 0.f, ss = 0.f;
#pragma unroll
    for (int i = 0; i < 16; ++i) { s += vals[i]; ss += vals[i] * vals[i]; }

    // vectorized gamma/beta loads (issued before the reduction chain)
    float4 gv[4], bv[4];
    gv[0] = *(const float4*)&g[t * 8];
    gv[1] = *(const float4*)&g[t * 8 + 4];
    gv[2] = *(const float4*)&g[(t + 256) * 8];
    gv[3] = *(const float4*)&g[(t + 256) * 8 + 4];
    bv[0] = *(const float4*)&be[t * 8];
    bv[1] = *(const float4*)&be[t * 8 + 4];
    bv[2] = *(const float4*)&be[(t + 256) * 8];
    bv[3] = *(const float4*)&be[(t + 256) * 8 + 4];

#pragma unroll
    for (int off = 32; off > 0; off >>= 1) {
        s += __shfl_down(s, off, 64);
        ss += __shfl_down(ss, off, 64);
    }
    if ((t & 63) == 0) { red[(t >> 6) * 2] = s; red[(t >> 6) * 2 + 1] = ss; }
    __syncthreads();
    s  = red[0] + red[2] + red[4] + red[6];
    ss = red[1] + red[3] + red[5] + red[7];
    const float mean = s * (1.f / HID_DIM);
    const float rstd = rsqrtf(ss * (1.f / HID_DIM) - mean * mean + 1e-5f);

    const float* gf = (const float*)gv;
    const float* bf = (const float*)bv;
#pragma unroll
    for (int j = 0; j < 2; ++j) {
        uint4 o;
        uint32_t* ow = (uint32_t*)&o;
#pragma unroll
        for (int q = 0; q < 4; ++q) {
            const int k = j * 8 + q * 2;
            float u0 = gelu_fast((vals[k]     - mean) * rstd * gf[k]     + bf[k]);
            float u1 = gelu_fast((vals[k + 1] - mean) * rstd * gf[k + 1] + bf[k + 1]);
            ow[q] = (uint32_t)f2b(u0) | ((uint32_t)f2b(u1) << 16);
        }
        *(uint4*)&hp[(t + j * 256) * 8] = o;
    }
}

// ---------- fused LN(1024) + GELU + weighted accumulate into out ----------
__global__ __launch_bounds__(256)
void ln_gelu_combine(const u16* __restrict__ y, const float* __restrict__ g,
                     const float* __restrict__ be, const float* __restrict__ wts,
                     float* __restrict__ out, int e, int first) {
    __shared__ float red[8];
    const int row = blockIdx.x;
    const u16* yp = y + (size_t)row * OUT_DIM;
    const int t = threadIdx.x;

    uint2 v = *(const uint2*)&yp[t * 4];
    float f0 = b2f((u16)(v.x & 0xffffu)), f1 = b2f((u16)(v.x >> 16));
    float f2 = b2f((u16)(v.y & 0xffffu)), f3 = b2f((u16)(v.y >> 16));
    float s = f0 + f1 + f2 + f3;
    float ss = f0 * f0 + f1 * f1 + f2 * f2 + f3 * f3;

    const int n = t * 4;
    float4 gv = *(const float4*)&g[n];
    float4 bvv = *(const float4*)&be[n];

#pragma unroll
    for (int off = 32; off > 0; off >>= 1) {
        s += __shfl_down(s, off, 64);
        ss += __shfl_down(ss, off, 64);
    }
    if ((t & 63) == 0) { red[(t >> 6) * 2] = s; red[(t >> 6) * 2 + 1] = ss; }
    __syncthreads();
    s  = red[0] + red[2] + red[4] + red[6];
    ss = red[1] + red[3] + red[5] + red[7];
    const float mean = s * (1.f / OUT_DIM);
    const float rstd = rsqrtf(ss * (1.f / OUT_DIM) - mean * mean + 1e-5f);

    const float w = wts[(size_t)row * NEXP + e];
    float4 o;
    if (first) { o.x = o.y = o.z = o.w = 0.f; }
    else       { o = *(const float4*)&out[(size_t)row * OUT_DIM + n]; }
    o.x += w * gelu_fast((f0 - mean) * rstd * gv.x + bvv.x);
    o.y += w * gelu_fast((f1 - mean) * rstd * gv.y + bvv.y);
    o.z += w * gelu_fast((f2 - mean) * rstd * gv.z + bvv.z);
    o.w += w * gelu_fast((f3 - mean) * rstd * gv.w + bvv.w);
    *(float4*)&out[(size_t)row * OUT_DIM + n] = o;
}

// ---------- launch ----------
extern "C" void kernel_launch(void* const* d_in, const int* in_sizes, int n_in,
                              void* d_out, int out_size, void* d_ws, size_t ws_size,
                              hipStream_t stream) {
    (void)in_sizes; (void)n_in; (void)out_size; (void)ws_size;
    const float* x   = (const float*)d_in[0];  // [8192,1024]
    const float* wts = (const float*)d_in[1];  // [8192,8]
    const float* W1  = (const float*)d_in[2];  // [8,1024,4096]
    const float* b1  = (const float*)d_in[3];  // [8,4096]
    const float* g1  = (const float*)d_in[4];  // [8,4096]
    const float* be1 = (const float*)d_in[5];  // [8,4096]
    const float* W2  = (const float*)d_in[6];  // [8,4096,1024]
    const float* b2  = (const float*)d_in[7];  // [8,1024]
    const float* g2  = (const float*)d_in[8];  // [8,1024]
    const float* be2 = (const float*)d_in[9];  // [8,1024]
    float* out = (float*)d_out;                // [8192,1024]

    // workspace carve (112 MB total)
    char* p = (char*)d_ws;
    u16* xb  = (u16*)p; p += (size_t)B_DIM * IN_DIM * 2;      // 16 MB
    u16* w1t = (u16*)p; p += (size_t)HID_DIM * IN_DIM * 2;    //  8 MB (per-expert slot)
    u16* w2t = (u16*)p; p += (size_t)OUT_DIM * HID_DIM * 2;   //  8 MB (per-expert slot)
    u16* h   = (u16*)p; p += (size_t)B_DIM * HID_DIM * 2;     // 64 MB
    u16* y   = (u16*)p; p += (size_t)B_DIM * OUT_DIM * 2;     // 16 MB

    cvt_bf16<<<(B_DIM * IN_DIM / 4 + 255) / 256, 256, 0, stream>>>(x, xb, B_DIM * IN_DIM / 4);

    for (int e = 0; e < NEXP; ++e) {
        // W1[e]: [IN,HID] -> w1t [HID,IN]
        transpose_cvt<<<dim3(HID_DIM / 32, IN_DIM / 32), 256, 0, stream>>>(
            W1 + (size_t)e * IN_DIM * HID_DIM, w1t, IN_DIM, HID_DIM);
        // h = xb @ W1[e] + b1[e]   (M=8192, N=4096, K=1024)
        gemm_bt_bias<<<dim3(HID_DIM / 128, B_DIM / 128), 256, 0, stream>>>(
            xb, w1t, b1 + (size_t)e * HID_DIM, h, B_DIM, HID_DIM, IN_DIM);
        // h = gelu(ln(h))
        ln_gelu_hid<<<B_DIM, 256, 0, stream>>>(h, g1 + (size_t)e * HID_DIM,
                                               be1 + (size_t)e * HID_DIM);
        // W2[e]: [HID,OUT] -> w2t [OUT,HID]
        transpose_cvt<<<dim3(OUT_DIM / 32, HID_DIM / 32), 256, 0, stream>>>(
            W2 + (size_t)e * HID_DIM * OUT_DIM, w2t, HID_DIM, OUT_DIM);
        // y = h @ W2[e] + b2[e]   (M=8192, N=1024, K=4096)
        gemm_bt_bias<<<dim3(OUT_DIM / 128, B_DIM / 128), 256, 0, stream>>>(
            h, w2t, b2 + (size_t)e * OUT_DIM, y, B_DIM, OUT_DIM, HID_DIM);
        // out (+)= wts[:,e] * gelu(ln(y))
        ln_gelu_combine<<<B_DIM, 256, 0, stream>>>(y, g2 + (size_t)e * OUT_DIM,
                                                   be2 + (size_t)e * OUT_DIM, wts, out,
                                                   e, e == 0 ? 1 : 0);
    }
}

// Round 3
// 2154.735 us; speedup vs baseline: 1.4061x; 1.0593x over previous
//
#include <hip/hip_runtime.h>
#include <cstdint>
#include <cstddef>

typedef unsigned short u16;
typedef float f32x4 __attribute__((ext_vector_type(4)));
typedef __bf16 bf16x8 __attribute__((ext_vector_type(8)));

#define B_DIM   8192
#define IN_DIM  1024
#define HID_DIM 4096
#define OUT_DIM 1024
#define NEXP    8

// ---------- helpers ----------
__device__ __forceinline__ u16 f2b(float f) {
    uint32_t u = __builtin_bit_cast(uint32_t, f);
    u += 0x7fffu + ((u >> 16) & 1u);      // RNE
    return (u16)(u >> 16);
}
__device__ __forceinline__ float b2f(u16 b) {
    uint32_t u = ((uint32_t)b) << 16;
    return __builtin_bit_cast(float, u);
}
// tanh-form GELU via one v_exp_f32: gelu(x) = x * e/(e+1), e = exp(2*y).
__device__ __forceinline__ float gelu_fast(float x) {
    float y = x * (0.7978845608f + 0.03567740814f * x * x);
    float a = fminf(y * 2.8853900818f, 80.0f);     // 2*log2(e)*y, clamp overflow
    float e = __builtin_amdgcn_exp2f(a);
    return x * e * __builtin_amdgcn_rcpf(e + 1.0f);
}
__device__ __forceinline__ void async_cp16(const void* g, void* l) {
    __builtin_amdgcn_global_load_lds(
        (const __attribute__((address_space(1))) void*)g,
        (__attribute__((address_space(3))) void*)l,
        16, 0, 0);
}

// ---------- fp32 -> bf16 convert ----------
__global__ __launch_bounds__(256)
void cvt_bf16(const float* __restrict__ in, u16* __restrict__ out, int n4) {
    int i = blockIdx.x * 256 + threadIdx.x;
    if (i >= n4) return;
    float4 v = *(const float4*)&in[(size_t)i * 4];
    uint2 o;
    o.x = (uint32_t)f2b(v.x) | ((uint32_t)f2b(v.y) << 16);
    o.y = (uint32_t)f2b(v.z) | ((uint32_t)f2b(v.w) << 16);
    *(uint2*)&out[(size_t)i * 4] = o;
}

// ---------- transpose both expert weights: [K,N] fp32 -> [N,K] bf16 ----------
// z=0: W1e [1024,4096] -> w1t [4096,1024]   (n-blocks on x: 128, k-blocks on y: 32)
// z=1: W2e [4096,1024] -> w2t [1024,4096]   (n-blocks on y: 32, k-blocks on x: 128)
__global__ __launch_bounds__(256)
void transpose_cvt2(const float* __restrict__ W1e, u16* __restrict__ w1t,
                    const float* __restrict__ W2e, u16* __restrict__ w2t) {
    __shared__ float tile[32][33];
    const float* W; u16* Wt; int K, N, n0, k0;
    if (blockIdx.z == 0) {
        W = W1e; Wt = w1t; K = IN_DIM; N = HID_DIM;
        n0 = blockIdx.x * 32; k0 = blockIdx.y * 32;
    } else {
        W = W2e; Wt = w2t; K = HID_DIM; N = OUT_DIM;
        n0 = blockIdx.y * 32; k0 = blockIdx.x * 32;
    }
    const int tx = threadIdx.x & 31, ty = threadIdx.x >> 5;   // ty 0..7
#pragma unroll
    for (int i = 0; i < 4; ++i) {
        int k = k0 + ty + i * 8;
        tile[ty + i * 8][tx] = W[(size_t)k * N + n0 + tx];
    }
    __syncthreads();
#pragma unroll
    for (int i = 0; i < 4; ++i) {
        int n = n0 + ty + i * 8;
        Wt[(size_t)n * K + k0 + tx] = f2b(tile[tx][ty + i * 8]);
    }
}

// ---------- bf16 GEMM: C[M,N] = A[M,K] * Bt[N,K]^T + bias, out bf16 ----------
// m97 structure: 128x128 tile, BK=32, global_load_lds width-16 staging,
// 16x16x32 bf16 MFMA, 4 waves in 2x2, each wave 64x64 (4x4 MFMA tiles).
// R3: +XOR chunk swizzle (kills 8-way ds_read_b128 bank conflicts),
//     +XCD-aware block swizzle (8-row-block A-stripe per XCD -> L2-resident).
__global__ __launch_bounds__(256)
void gemm_bt_bias(const u16* __restrict__ A, const u16* __restrict__ Bt,
                  const float* __restrict__ bias, u16* __restrict__ C,
                  int M, int N, int K) {
    __shared__ __attribute__((aligned(16))) u16 sA[128 * 32];
    __shared__ __attribute__((aligned(16))) u16 sB[128 * 32];

    const int tid  = threadIdx.x;
    const int wid  = tid >> 6;
    const int lane = tid & 63;
    const int quad = lane >> 4;
    const int lr   = lane & 15;
    const int wm   = wid & 1;
    const int wn   = wid >> 1;

    // XCD-aware supertile swizzle: bid&7 == XCD (HW round-robin). Give each
    // XCD a contiguous stripe of NY/8 row-blocks so its resident blocks share
    // a small A working set (2 MB @ K=1024) that fits the 4 MB per-XCD L2.
    const int NX = gridDim.x, NY = gridDim.y;
    const int bid = blockIdx.y * NX + blockIdx.x;
    const int xcd = bid & 7;
    const int j   = bid >> 3;
    const int yl  = j / NX;
    const int bx  = j - yl * NX;
    const int by  = xcd * (NY >> 3) + yl;

    const int m0 = by * 128;
    const int n0 = bx * 128;

    const int sr = lane >> 2;                                  // 0..15 row
    const int scl = ((lane & 3) ^ ((lane >> 3) & 3)) * 8;      // swizzled chunk
    const int qsw = (lr >> 1) & 3;                             // read-side XOR

    const u16* Ag = A + (size_t)m0 * K;
    const u16* Bg = Bt + (size_t)n0 * K;

    f32x4 acc[4][4] = {};

    for (int k0 = 0; k0 < K; k0 += 32) {
#pragma unroll
        for (int i = 0; i < 2; ++i) {
            const int rb = wid * 32 + i * 16;
            async_cp16(Ag + (size_t)(rb + sr) * K + k0 + scl, &sA[rb * 32]);
        }
#pragma unroll
        for (int i = 0; i < 2; ++i) {
            const int rb = wid * 32 + i * 16;
            async_cp16(Bg + (size_t)(rb + sr) * K + k0 + scl, &sB[rb * 32]);
        }
        __syncthreads();

        bf16x8 af[4], bfr[4];
#pragma unroll
        for (int mi = 0; mi < 4; ++mi)
            af[mi] = *(const bf16x8*)&sA[(wm * 64 + mi * 16 + lr) * 32 + ((quad ^ qsw) * 8)];
#pragma unroll
        for (int ni = 0; ni < 4; ++ni)
            bfr[ni] = *(const bf16x8*)&sB[(wn * 64 + ni * 16 + lr) * 32 + ((quad ^ qsw) * 8)];

#pragma unroll
        for (int mi = 0; mi < 4; ++mi)
#pragma unroll
            for (int ni = 0; ni < 4; ++ni)
                acc[mi][ni] = __builtin_amdgcn_mfma_f32_16x16x32_bf16(
                    af[mi], bfr[ni], acc[mi][ni], 0, 0, 0);

        __syncthreads();
    }

    // epilogue: D col = lane&15, row = quad*4 + reg
#pragma unroll
    for (int ni = 0; ni < 4; ++ni) {
        const int n = n0 + wn * 64 + ni * 16 + lr;
        const float bv = bias[n];
#pragma unroll
        for (int mi = 0; mi < 4; ++mi) {
            const int mr = m0 + wm * 64 + mi * 16 + quad * 4;
#pragma unroll
            for (int r = 0; r < 4; ++r) {
                C[(size_t)(mr + r) * N + n] = f2b(acc[mi][ni][r] + bv);
            }
        }
    }
}

// ---------- fused LN(4096) + GELU, in-place on bf16 h ----------
__global__ __launch_bounds__(256)
void ln_gelu_hid(u16* __restrict__ h, const float* __restrict__ g,
                 const float* __restrict__ be) {
    __shared__ float red[8];
    const int row = blockIdx.x;
    u16* hp = h + (size_t)row * HID_DIM;
    const int t = threadIdx.x;

    uint4 v0 = *(const uint4*)&hp[t * 8];
    uint4 v1 = *(const uint4*)&hp[(t + 256) * 8];

    float vals[16];
    {
        const uint32_t w0[4] = {v0.x, v0.y, v0.z, v0.w};
        const uint32_t w1[4] = {v1.x, v1.y, v1.z, v1.w};
#pragma unroll
        for (int q = 0; q < 4; ++q) {
            vals[q * 2]     = b2f((u16)(w0[q] & 0xffffu));
            vals[q * 2 + 1] = b2f((u16)(w0[q] >> 16));
            vals[8 + q * 2]     = b2f((u16)(w1[q] & 0xffffu));
            vals[8 + q * 2 + 1] = b2f((u16)(w1[q] >> 16));
        }
    }
    float s = 0.f, ss = 0.f;
#pragma unroll
    for (int i = 0; i < 16; ++i) { s += vals[i]; ss += vals[i] * vals[i]; }

    float4 gv[4], bv[4];
    gv[0] = *(const float4*)&g[t * 8];
    gv[1] = *(const float4*)&g[t * 8 + 4];
    gv[2] = *(const float4*)&g[(t + 256) * 8];
    gv[3] = *(const float4*)&g[(t + 256) * 8 + 4];
    bv[0] = *(const float4*)&be[t * 8];
    bv[1] = *(const float4*)&be[t * 8 + 4];
    bv[2] = *(const float4*)&be[(t + 256) * 8];
    bv[3] = *(const float4*)&be[(t + 256) * 8 + 4];

#pragma unroll
    for (int off = 32; off > 0; off >>= 1) {
        s += __shfl_down(s, off, 64);
        ss += __shfl_down(ss, off, 64);
    }
    if ((t & 63) == 0) { red[(t >> 6) * 2] = s; red[(t >> 6) * 2 + 1] = ss; }
    __syncthreads();
    s  = red[0] + red[2] + red[4] + red[6];
    ss = red[1] + red[3] + red[5] + red[7];
    const float mean = s * (1.f / HID_DIM);
    const float rstd = rsqrtf(ss * (1.f / HID_DIM) - mean * mean + 1e-5f);

    const float* gf = (const float*)gv;
    const float* bf = (const float*)bv;
#pragma unroll
    for (int j = 0; j < 2; ++j) {
        uint4 o;
        uint32_t* ow = (uint32_t*)&o;
#pragma unroll
        for (int q = 0; q < 4; ++q) {
            const int k = j * 8 + q * 2;
            float u0 = gelu_fast((vals[k]     - mean) * rstd * gf[k]     + bf[k]);
            float u1 = gelu_fast((vals[k + 1] - mean) * rstd * gf[k + 1] + bf[k + 1]);
            ow[q] = (uint32_t)f2b(u0) | ((uint32_t)f2b(u1) << 16);
        }
        *(uint4*)&hp[(t + j * 256) * 8] = o;
    }
}

// ---------- fused LN(1024) + GELU + weighted accumulate into out ----------
__global__ __launch_bounds__(256)
void ln_gelu_combine(const u16* __restrict__ y, const float* __restrict__ g,
                     const float* __restrict__ be, const float* __restrict__ wts,
                     float* __restrict__ out, int e, int first) {
    __shared__ float red[8];
    const int row = blockIdx.x;
    const u16* yp = y + (size_t)row * OUT_DIM;
    const int t = threadIdx.x;

    uint2 v = *(const uint2*)&yp[t * 4];
    float f0 = b2f((u16)(v.x & 0xffffu)), f1 = b2f((u16)(v.x >> 16));
    float f2 = b2f((u16)(v.y & 0xffffu)), f3 = b2f((u16)(v.y >> 16));
    float s = f0 + f1 + f2 + f3;
    float ss = f0 * f0 + f1 * f1 + f2 * f2 + f3 * f3;

    const int n = t * 4;
    float4 gv = *(const float4*)&g[n];
    float4 bvv = *(const float4*)&be[n];

#pragma unroll
    for (int off = 32; off > 0; off >>= 1) {
        s += __shfl_down(s, off, 64);
        ss += __shfl_down(ss, off, 64);
    }
    if ((t & 63) == 0) { red[(t >> 6) * 2] = s; red[(t >> 6) * 2 + 1] = ss; }
    __syncthreads();
    s  = red[0] + red[2] + red[4] + red[6];
    ss = red[1] + red[3] + red[5] + red[7];
    const float mean = s * (1.f / OUT_DIM);
    const float rstd = rsqrtf(ss * (1.f / OUT_DIM) - mean * mean + 1e-5f);

    const float w = wts[(size_t)row * NEXP + e];
    float4 o;
    if (first) { o.x = o.y = o.z = o.w = 0.f; }
    else       { o = *(const float4*)&out[(size_t)row * OUT_DIM + n]; }
    o.x += w * gelu_fast((f0 - mean) * rstd * gv.x + bvv.x);
    o.y += w * gelu_fast((f1 - mean) * rstd * gv.y + bvv.y);
    o.z += w * gelu_fast((f2 - mean) * rstd * gv.z + bvv.z);
    o.w += w * gelu_fast((f3 - mean) * rstd * gv.w + bvv.w);
    *(float4*)&out[(size_t)row * OUT_DIM + n] = o;
}

// ---------- launch ----------
extern "C" void kernel_launch(void* const* d_in, const int* in_sizes, int n_in,
                              void* d_out, int out_size, void* d_ws, size_t ws_size,
                              hipStream_t stream) {
    (void)in_sizes; (void)n_in; (void)out_size; (void)ws_size;
    const float* x   = (const float*)d_in[0];  // [8192,1024]
    const float* wts = (const float*)d_in[1];  // [8192,8]
    const float* W1  = (const float*)d_in[2];  // [8,1024,4096]
    const float* b1  = (const float*)d_in[3];  // [8,4096]
    const float* g1  = (const float*)d_in[4];  // [8,4096]
    const float* be1 = (const float*)d_in[5];  // [8,4096]
    const float* W2  = (const float*)d_in[6];  // [8,4096,1024]
    const float* b2  = (const float*)d_in[7];  // [8,1024]
    const float* g2  = (const float*)d_in[8];  // [8,1024]
    const float* be2 = (const float*)d_in[9];  // [8,1024]
    float* out = (float*)d_out;                // [8192,1024]

    // workspace carve (112 MB total)
    char* p = (char*)d_ws;
    u16* xb  = (u16*)p; p += (size_t)B_DIM * IN_DIM * 2;      // 16 MB
    u16* w1t = (u16*)p; p += (size_t)HID_DIM * IN_DIM * 2;    //  8 MB (per-expert slot)
    u16* w2t = (u16*)p; p += (size_t)OUT_DIM * HID_DIM * 2;   //  8 MB (per-expert slot)
    u16* h   = (u16*)p; p += (size_t)B_DIM * HID_DIM * 2;     // 64 MB
    u16* y   = (u16*)p; p += (size_t)B_DIM * OUT_DIM * 2;     // 16 MB

    cvt_bf16<<<(B_DIM * IN_DIM / 4 + 255) / 256, 256, 0, stream>>>(x, xb, B_DIM * IN_DIM / 4);

    for (int e = 0; e < NEXP; ++e) {
        // transpose+convert both weight matrices for this expert
        transpose_cvt2<<<dim3(HID_DIM / 32, IN_DIM / 32, 2), 256, 0, stream>>>(
            W1 + (size_t)e * IN_DIM * HID_DIM, w1t,
            W2 + (size_t)e * HID_DIM * OUT_DIM, w2t);
        // h = xb @ W1[e] + b1[e]   (M=8192, N=4096, K=1024)
        gemm_bt_bias<<<dim3(HID_DIM / 128, B_DIM / 128), 256, 0, stream>>>(
            xb, w1t, b1 + (size_t)e * HID_DIM, h, B_DIM, HID_DIM, IN_DIM);
        // h = gelu(ln(h))
        ln_gelu_hid<<<B_DIM, 256, 0, stream>>>(h, g1 + (size_t)e * HID_DIM,
                                               be1 + (size_t)e * HID_DIM);
        // y = h @ W2[e] + b2[e]   (M=8192, N=1024, K=4096)
        gemm_bt_bias<<<dim3(OUT_DIM / 128, B_DIM / 128), 256, 0, stream>>>(
            h, w2t, b2 + (size_t)e * OUT_DIM, y, B_DIM, OUT_DIM, HID_DIM);
        // out (+)= wts[:,e] * gelu(ln(y))
        ln_gelu_combine<<<B_DIM, 256, 0, stream>>>(y, g2 + (size_t)e * OUT_DIM,
                                                   be2 + (size_t)e * OUT_DIM, wts, out,
                                                   e, e == 0 ? 1 : 0);
    }
}

// Round 4
// 1965.359 us; speedup vs baseline: 1.5416x; 1.0964x over previous
//
#include <hip/hip_runtime.h>
#include <cstdint>
#include <cstddef>

typedef unsigned short u16;
typedef float f32x4 __attribute__((ext_vector_type(4)));
typedef __bf16 bf16x8 __attribute__((ext_vector_type(8)));

#define B_DIM   8192
#define IN_DIM  1024
#define HID_DIM 4096
#define OUT_DIM 1024
#define NEXP    8

// ---------- helpers ----------
__device__ __forceinline__ u16 f2b(float f) {
    uint32_t u = __builtin_bit_cast(uint32_t, f);
    u += 0x7fffu + ((u >> 16) & 1u);      // RNE
    return (u16)(u >> 16);
}
__device__ __forceinline__ float b2f(u16 b) {
    uint32_t u = ((uint32_t)b) << 16;
    return __builtin_bit_cast(float, u);
}
// tanh-form GELU via one v_exp_f32: gelu(x) = x * e/(e+1), e = exp(2*y).
__device__ __forceinline__ float gelu_fast(float x) {
    float y = x * (0.7978845608f + 0.03567740814f * x * x);
    float a = fminf(y * 2.8853900818f, 80.0f);     // 2*log2(e)*y, clamp overflow
    float e = __builtin_amdgcn_exp2f(a);
    return x * e * __builtin_amdgcn_rcpf(e + 1.0f);
}
__device__ __forceinline__ void async_cp16(const void* g, void* l) {
    __builtin_amdgcn_global_load_lds(
        (const __attribute__((address_space(1))) void*)g,
        (__attribute__((address_space(3))) void*)l,
        16, 0, 0);
}

// ---------- fp32 -> bf16 convert ----------
__global__ __launch_bounds__(256)
void cvt_bf16(const float* __restrict__ in, u16* __restrict__ out, int n4) {
    int i = blockIdx.x * 256 + threadIdx.x;
    if (i >= n4) return;
    float4 v = *(const float4*)&in[(size_t)i * 4];
    uint2 o;
    o.x = (uint32_t)f2b(v.x) | ((uint32_t)f2b(v.y) << 16);
    o.y = (uint32_t)f2b(v.z) | ((uint32_t)f2b(v.w) << 16);
    *(uint2*)&out[(size_t)i * 4] = o;
}

// ---------- transpose both expert weights: [K,N] fp32 -> [N,K] bf16 ----------
__global__ __launch_bounds__(256)
void transpose_cvt2(const float* __restrict__ W1e, u16* __restrict__ w1t,
                    const float* __restrict__ W2e, u16* __restrict__ w2t) {
    __shared__ float tile[32][33];
    const float* W; u16* Wt; int K, N, n0, k0;
    if (blockIdx.z == 0) {
        W = W1e; Wt = w1t; K = IN_DIM; N = HID_DIM;
        n0 = blockIdx.x * 32; k0 = blockIdx.y * 32;
    } else {
        W = W2e; Wt = w2t; K = HID_DIM; N = OUT_DIM;
        n0 = blockIdx.y * 32; k0 = blockIdx.x * 32;
    }
    const int tx = threadIdx.x & 31, ty = threadIdx.x >> 5;   // ty 0..7
#pragma unroll
    for (int i = 0; i < 4; ++i) {
        int k = k0 + ty + i * 8;
        tile[ty + i * 8][tx] = W[(size_t)k * N + n0 + tx];
    }
    __syncthreads();
#pragma unroll
    for (int i = 0; i < 4; ++i) {
        int n = n0 + ty + i * 8;
        Wt[(size_t)n * K + k0 + tx] = f2b(tile[tx][ty + i * 8]);
    }
}

// ---------- bf16 GEMM: C[M,N] = A[M,K] * Bt[N,K]^T + bias, out bf16 ----------
// m97 structure + R3 swizzles; R4: two BK=32 subtiles staged per barrier
// (effective BK=64 -> half the barrier/vmcnt-drain count, 32 MFMA per sync,
// LDS 32 KB = 5 blocks/CU LDS-wise), epilogue reordered ni-innermost for
// L2 write-combining.
__global__ __launch_bounds__(256)
void gemm_bt_bias(const u16* __restrict__ A, const u16* __restrict__ Bt,
                  const float* __restrict__ bias, u16* __restrict__ C,
                  int M, int N, int K) {
    __shared__ __attribute__((aligned(16))) u16 sA[2][128 * 32];
    __shared__ __attribute__((aligned(16))) u16 sB[2][128 * 32];

    const int tid  = threadIdx.x;
    const int wid  = tid >> 6;
    const int lane = tid & 63;
    const int quad = lane >> 4;
    const int lr   = lane & 15;
    const int wm   = wid & 1;
    const int wn   = wid >> 1;

    // XCD-aware supertile swizzle (bid&7 == XCD round-robin).
    const int NX = gridDim.x, NY = gridDim.y;
    const int bid = blockIdx.y * NX + blockIdx.x;
    const int xcd = bid & 7;
    const int j   = bid >> 3;
    const int yl  = j / NX;
    const int bx  = j - yl * NX;
    const int by  = xcd * (NY >> 3) + yl;

    const int m0 = by * 128;
    const int n0 = bx * 128;

    const int sr  = lane >> 2;                                 // 0..15 row
    const int scl = ((lane & 3) ^ ((lane >> 3) & 3)) * 8;      // swizzled chunk
    const int qsw = (lr >> 1) & 3;                             // read-side XOR

    const u16* Ag = A + (size_t)m0 * K;
    const u16* Bg = Bt + (size_t)n0 * K;

    f32x4 acc[4][4] = {};

    for (int k0 = 0; k0 < K; k0 += 64) {
        // stage two BK=32 subtiles (8 async_cp16 per thread total)
#pragma unroll
        for (int s = 0; s < 2; ++s) {
#pragma unroll
            for (int i = 0; i < 2; ++i) {
                const int rb = wid * 32 + i * 16;
                async_cp16(Ag + (size_t)(rb + sr) * K + k0 + s * 32 + scl,
                           &sA[s][rb * 32]);
                async_cp16(Bg + (size_t)(rb + sr) * K + k0 + s * 32 + scl,
                           &sB[s][rb * 32]);
            }
        }
        __syncthreads();

#pragma unroll
        for (int s = 0; s < 2; ++s) {
            bf16x8 af[4], bfr[4];
#pragma unroll
            for (int mi = 0; mi < 4; ++mi)
                af[mi] = *(const bf16x8*)
                    &sA[s][(wm * 64 + mi * 16 + lr) * 32 + ((quad ^ qsw) * 8)];
#pragma unroll
            for (int ni = 0; ni < 4; ++ni)
                bfr[ni] = *(const bf16x8*)
                    &sB[s][(wn * 64 + ni * 16 + lr) * 32 + ((quad ^ qsw) * 8)];

#pragma unroll
            for (int mi = 0; mi < 4; ++mi)
#pragma unroll
                for (int ni = 0; ni < 4; ++ni)
                    acc[mi][ni] = __builtin_amdgcn_mfma_f32_16x16x32_bf16(
                        af[mi], bfr[ni], acc[mi][ni], 0, 0, 0);
        }

        __syncthreads();
    }

    // epilogue: D col = lane&15, row = quad*4 + reg. ni innermost so the
    // 4x32B segments of each row's 128B span issue back-to-back.
    float bvv[4];
#pragma unroll
    for (int ni = 0; ni < 4; ++ni)
        bvv[ni] = bias[n0 + wn * 64 + ni * 16 + lr];

#pragma unroll
    for (int mi = 0; mi < 4; ++mi) {
        const int mr = m0 + wm * 64 + mi * 16 + quad * 4;
#pragma unroll
        for (int r = 0; r < 4; ++r) {
            u16* Crow = C + (size_t)(mr + r) * N + n0 + wn * 64 + lr;
#pragma unroll
            for (int ni = 0; ni < 4; ++ni)
                Crow[ni * 16] = f2b(acc[mi][ni][r] + bvv[ni]);
        }
    }
}

// ---------- fused LN(4096) + GELU, in-place on bf16 h ----------
__global__ __launch_bounds__(256)
void ln_gelu_hid(u16* __restrict__ h, const float* __restrict__ g,
                 const float* __restrict__ be) {
    __shared__ float red[8];
    const int row = blockIdx.x;
    u16* hp = h + (size_t)row * HID_DIM;
    const int t = threadIdx.x;

    uint4 v0 = *(const uint4*)&hp[t * 8];
    uint4 v1 = *(const uint4*)&hp[(t + 256) * 8];

    float vals[16];
    {
        const uint32_t w0[4] = {v0.x, v0.y, v0.z, v0.w};
        const uint32_t w1[4] = {v1.x, v1.y, v1.z, v1.w};
#pragma unroll
        for (int q = 0; q < 4; ++q) {
            vals[q * 2]     = b2f((u16)(w0[q] & 0xffffu));
            vals[q * 2 + 1] = b2f((u16)(w0[q] >> 16));
            vals[8 + q * 2]     = b2f((u16)(w1[q] & 0xffffu));
            vals[8 + q * 2 + 1] = b2f((u16)(w1[q] >> 16));
        }
    }
    float s = 0.f, ss = 0.f;
#pragma unroll
    for (int i = 0; i < 16; ++i) { s += vals[i]; ss += vals[i] * vals[i]; }

    float4 gv[4], bv[4];
    gv[0] = *(const float4*)&g[t * 8];
    gv[1] = *(const float4*)&g[t * 8 + 4];
    gv[2] = *(const float4*)&g[(t + 256) * 8];
    gv[3] = *(const float4*)&g[(t + 256) * 8 + 4];
    bv[0] = *(const float4*)&be[t * 8];
    bv[1] = *(const float4*)&be[t * 8 + 4];
    bv[2] = *(const float4*)&be[(t + 256) * 8];
    bv[3] = *(const float4*)&be[(t + 256) * 8 + 4];

#pragma unroll
    for (int off = 32; off > 0; off >>= 1) {
        s += __shfl_down(s, off, 64);
        ss += __shfl_down(ss, off, 64);
    }
    if ((t & 63) == 0) { red[(t >> 6) * 2] = s; red[(t >> 6) * 2 + 1] = ss; }
    __syncthreads();
    s  = red[0] + red[2] + red[4] + red[6];
    ss = red[1] + red[3] + red[5] + red[7];
    const float mean = s * (1.f / HID_DIM);
    const float rstd = rsqrtf(ss * (1.f / HID_DIM) - mean * mean + 1e-5f);

    const float* gf = (const float*)gv;
    const float* bf = (const float*)bv;
#pragma unroll
    for (int j = 0; j < 2; ++j) {
        uint4 o;
        uint32_t* ow = (uint32_t*)&o;
#pragma unroll
        for (int q = 0; q < 4; ++q) {
            const int k = j * 8 + q * 2;
            float u0 = gelu_fast((vals[k]     - mean) * rstd * gf[k]     + bf[k]);
            float u1 = gelu_fast((vals[k + 1] - mean) * rstd * gf[k + 1] + bf[k + 1]);
            ow[q] = (uint32_t)f2b(u0) | ((uint32_t)f2b(u1) << 16);
        }
        *(uint4*)&hp[(t + j * 256) * 8] = o;
    }
}

// ---------- fused LN(1024) + GELU + weighted accumulate into out ----------
__global__ __launch_bounds__(256)
void ln_gelu_combine(const u16* __restrict__ y, const float* __restrict__ g,
                     const float* __restrict__ be, const float* __restrict__ wts,
                     float* __restrict__ out, int e, int first) {
    __shared__ float red[8];
    const int row = blockIdx.x;
    const u16* yp = y + (size_t)row * OUT_DIM;
    const int t = threadIdx.x;

    uint2 v = *(const uint2*)&yp[t * 4];
    float f0 = b2f((u16)(v.x & 0xffffu)), f1 = b2f((u16)(v.x >> 16));
    float f2 = b2f((u16)(v.y & 0xffffu)), f3 = b2f((u16)(v.y >> 16));
    float s = f0 + f1 + f2 + f3;
    float ss = f0 * f0 + f1 * f1 + f2 * f2 + f3 * f3;

    const int n = t * 4;
    float4 gv = *(const float4*)&g[n];
    float4 bvv = *(const float4*)&be[n];

#pragma unroll
    for (int off = 32; off > 0; off >>= 1) {
        s += __shfl_down(s, off, 64);
        ss += __shfl_down(ss, off, 64);
    }
    if ((t & 63) == 0) { red[(t >> 6) * 2] = s; red[(t >> 6) * 2 + 1] = ss; }
    __syncthreads();
    s  = red[0] + red[2] + red[4] + red[6];
    ss = red[1] + red[3] + red[5] + red[7];
    const float mean = s * (1.f / OUT_DIM);
    const float rstd = rsqrtf(ss * (1.f / OUT_DIM) - mean * mean + 1e-5f);

    const float w = wts[(size_t)row * NEXP + e];
    float4 o;
    if (first) { o.x = o.y = o.z = o.w = 0.f; }
    else       { o = *(const float4*)&out[(size_t)row * OUT_DIM + n]; }
    o.x += w * gelu_fast((f0 - mean) * rstd * gv.x + bvv.x);
    o.y += w * gelu_fast((f1 - mean) * rstd * gv.y + bvv.y);
    o.z += w * gelu_fast((f2 - mean) * rstd * gv.z + bvv.z);
    o.w += w * gelu_fast((f3 - mean) * rstd * gv.w + bvv.w);
    *(float4*)&out[(size_t)row * OUT_DIM + n] = o;
}

// ---------- launch ----------
extern "C" void kernel_launch(void* const* d_in, const int* in_sizes, int n_in,
                              void* d_out, int out_size, void* d_ws, size_t ws_size,
                              hipStream_t stream) {
    (void)in_sizes; (void)n_in; (void)out_size; (void)ws_size;
    const float* x   = (const float*)d_in[0];  // [8192,1024]
    const float* wts = (const float*)d_in[1];  // [8192,8]
    const float* W1  = (const float*)d_in[2];  // [8,1024,4096]
    const float* b1  = (const float*)d_in[3];  // [8,4096]
    const float* g1  = (const float*)d_in[4];  // [8,4096]
    const float* be1 = (const float*)d_in[5];  // [8,4096]
    const float* W2  = (const float*)d_in[6];  // [8,4096,1024]
    const float* b2  = (const float*)d_in[7];  // [8,1024]
    const float* g2  = (const float*)d_in[8];  // [8,1024]
    const float* be2 = (const float*)d_in[9];  // [8,1024]
    float* out = (float*)d_out;                // [8192,1024]

    // workspace carve (112 MB total)
    char* p = (char*)d_ws;
    u16* xb  = (u16*)p; p += (size_t)B_DIM * IN_DIM * 2;      // 16 MB
    u16* w1t = (u16*)p; p += (size_t)HID_DIM * IN_DIM * 2;    //  8 MB (per-expert slot)
    u16* w2t = (u16*)p; p += (size_t)OUT_DIM * HID_DIM * 2;   //  8 MB (per-expert slot)
    u16* h   = (u16*)p; p += (size_t)B_DIM * HID_DIM * 2;     // 64 MB
    u16* y   = (u16*)p; p += (size_t)B_DIM * OUT_DIM * 2;     // 16 MB

    cvt_bf16<<<(B_DIM * IN_DIM / 4 + 255) / 256, 256, 0, stream>>>(x, xb, B_DIM * IN_DIM / 4);

    for (int e = 0; e < NEXP; ++e) {
        transpose_cvt2<<<dim3(HID_DIM / 32, IN_DIM / 32, 2), 256, 0, stream>>>(
            W1 + (size_t)e * IN_DIM * HID_DIM, w1t,
            W2 + (size_t)e * HID_DIM * OUT_DIM, w2t);
        // h = xb @ W1[e] + b1[e]   (M=8192, N=4096, K=1024)
        gemm_bt_bias<<<dim3(HID_DIM / 128, B_DIM / 128), 256, 0, stream>>>(
            xb, w1t, b1 + (size_t)e * HID_DIM, h, B_DIM, HID_DIM, IN_DIM);
        // h = gelu(ln(h))
        ln_gelu_hid<<<B_DIM, 256, 0, stream>>>(h, g1 + (size_t)e * HID_DIM,
                                               be1 + (size_t)e * HID_DIM);
        // y = h @ W2[e] + b2[e]   (M=8192, N=1024, K=4096)
        gemm_bt_bias<<<dim3(OUT_DIM / 128, B_DIM / 128), 256, 0, stream>>>(
            h, w2t, b2 + (size_t)e * OUT_DIM, y, B_DIM, OUT_DIM, HID_DIM);
        // out (+)= wts[:,e] * gelu(ln(y))
        ln_gelu_combine<<<B_DIM, 256, 0, stream>>>(y, g2 + (size_t)e * OUT_DIM,
                                                   be2 + (size_t)e * OUT_DIM, wts, out,
                                                   e, e == 0 ? 1 : 0);
    }
}